// Round 5
// baseline (394.360 us; speedup 1.0000x reference)
//
#include <hip/hip_runtime.h>
#include <hip/hip_fp16.h>

// GCN layer: relu(A1·(xW1) + A2·(xW2) + b), B=4, N=50000, F=64, E=800000.
// fp32 in/out, int32 indices. pre stored fp16 (gather operand; fp32 accum).
// Row space concatenated over both supports: srow in [0, 2N); bucket =
// srow/6250 (16 buckets = 2 supports x 8 octants). Build chain:
//   build_wfrag (MFMA B-fragments of W1/W2, split fp16 hi/lo)
//   memset -> bin_edges (bucket bin + fire-and-forget row counts)
//          -> scan_partial -> scan_sums -> make_ptrs (abs rowptr + cursor)
//          -> scatter (octant-pinned; claims row slot via cursor atomic)
//   then gemm_mfma (pre1/pre2 overwrite the dead bin arrays) -> fused spmm.
// R9: gemm on split-fp16 3-term MFMA; accuracy = fp32 GEMM. 398->347us.
// R10: dual-stream spmm + nt stores: NEUTRAL. spmm is memory-system
//     throughput-bound, not MLP-bound.
// R11: s1/s2 phase-split + gemm LDS-drop: REGRESSED. Reverted. Diagnostic:
//     bin exposed at 78us, occ 25%, VALU 2% -> atomic-return-latency bound.
// R12: bin BIN_U 8->2: NEUTRAL (more waves but fewer atomics/thread in
//     flight; 96 vs 64 in-flight/CU — a wash). Return dependency is the wall.
// R13: remove the return dependency. Row counts become fire-and-forget
//     (no round-trip stall); the slot-claim atomic moves to scatter
//     (full occupancy, ~2 iters/thread, overlapped with bepack stream).
//     Slot order within a row becomes nondeterministic — safe: fp32 add
//     commutes; absmax 0.125 is fp16 quantization (R10 order-change proof).
#define NB 4
#define NN 50000
#define FF 64
#define NN2 (2 * NN)
#define OCT 6250
#define NBKT 16
#define SCAN_BLOCKS ((NN2 + 255) / 256)   // 391
#define BIN_U 4
#define BIN_T 256
#define BIN_CHUNK (BIN_U * BIN_T)         // 1024 edges per block
#define STP 68                            // padded staging stride (halves)

typedef _Float16 half8 __attribute__((ext_vector_type(8)));
typedef float    f32x4 __attribute__((ext_vector_type(4)));

// ---------------- W fragments for mfma_f32_16x16x32_f16 ---------------------
// B-operand layout (16x16x32): lane l holds col = l&15, k = (l>>4)*8 + j,
// j=0..7, packed k-ascending as half8 (4 VGPRs). 32 frags:
//   frag = s*16 + part*8 + ko*4 + fo   (s: support, part: hi/lo split,
//   ko: k-half 0..1, fo: 16-col output tile 0..3).  32*64*16B = 32 KB.
__global__ void build_wfrag(const float* __restrict__ W1, const float* __restrict__ W2,
                            uint4* __restrict__ wfrag) {
    const int t = blockIdx.x * 256 + threadIdx.x;    // 0..2047
    if (t >= 32 * 64) return;
    const int lane = t & 63;
    const int frag = t >> 6;
    const int fo   = frag & 3;
    const int ko   = (frag >> 2) & 1;
    const int part = (frag >> 3) & 1;
    const int s    = frag >> 4;
    const float* W = s ? W2 : W1;
    const int col = fo * 16 + (lane & 15);
    const int k0  = ko * 32 + (lane >> 4) * 8;
    half8 h;
#pragma unroll
    for (int j = 0; j < 8; ++j) {
        const float w = W[(k0 + j) * FF + col];
        const _Float16 hi = (_Float16)w;
        h[j] = part ? (_Float16)(w - (float)hi) : hi;
    }
    wfrag[t] = __builtin_bit_cast(uint4, h);
}

// ---------------- MFMA GEMM: pre{1,2}[n][f] = half4{ x[b][n][:]·W{1,2}[:,f] }
// Block = 512 threads = 8 waves; wave w: support s=w>>2, batch b=w&3,
// rows r0..r0+15. A-operand (x rows, fp32->hi/lo fp16): lane l holds
// row = l&15, k = (l>>4)*8+j. 24 MFMA/wave. D: row=(l>>4)*4+m, col=l&15.
// Output staged in LDS (stride 68 halves: conflict-free acc stores) to
// repack the 4 batches into the uint2 fp16 layout spmm_fused consumes.
__global__ __launch_bounds__(512, 2) void gemm_mfma(const float* __restrict__ x,
                                                    const uint4* __restrict__ wfrag,
                                                    uint2* __restrict__ pre1,
                                                    uint2* __restrict__ pre2) {
    __shared__ uint4 fr[32][64];            // 32 KB: W fragments
    __shared__ _Float16 st[2][4][16][STP];  // 17.4 KB: output staging
    const int tid = threadIdx.x;
#pragma unroll
    for (int i = 0; i < 4; ++i) {           // stage all 32 frags, coalesced
        const int idx = tid + i * 512;
        fr[idx >> 6][idx & 63] = wfrag[idx];
    }
    const int wid = tid >> 6, lane = tid & 63;
    const int s = wid >> 2, b = wid & 3;
    const int r0 = blockIdx.x * 16;
    const int l15 = lane & 15, g = lane >> 4;
    // A: 64B/lane of x row l15, fully coalesced across the wave (4 KB/wave)
    const float4* xp = (const float4*)(x + ((size_t)b * NN + r0 + l15) * FF);
    const float4 A0 = xp[g * 2],     A1 = xp[g * 2 + 1];
    const float4 A2 = xp[8 + g * 2], A3 = xp[8 + g * 2 + 1];
    const float av[16] = {A0.x, A0.y, A0.z, A0.w, A1.x, A1.y, A1.z, A1.w,
                          A2.x, A2.y, A2.z, A2.w, A3.x, A3.y, A3.z, A3.w};
    half8 ahi[2], alo[2];
#pragma unroll
    for (int ko = 0; ko < 2; ++ko)
#pragma unroll
        for (int j = 0; j < 8; ++j) {
            const float v = av[ko * 8 + j];
            const _Float16 hi = (_Float16)v;
            ahi[ko][j] = hi;
            alo[ko][j] = (_Float16)(v - (float)hi);
        }
    __syncthreads();
    f32x4 acc[4] = {{0.f, 0.f, 0.f, 0.f}, {0.f, 0.f, 0.f, 0.f},
                    {0.f, 0.f, 0.f, 0.f}, {0.f, 0.f, 0.f, 0.f}};
#pragma unroll
    for (int fo = 0; fo < 4; ++fo)
#pragma unroll
        for (int ko = 0; ko < 2; ++ko) {
            const half8 whi = *(const half8*)&fr[s * 16 + ko * 4 + fo][lane];
            const half8 wlo = *(const half8*)&fr[s * 16 + 8 + ko * 4 + fo][lane];
            acc[fo] = __builtin_amdgcn_mfma_f32_16x16x32_f16(ahi[ko], whi, acc[fo], 0, 0, 0);
            acc[fo] = __builtin_amdgcn_mfma_f32_16x16x32_f16(alo[ko], whi, acc[fo], 0, 0, 0);
            acc[fo] = __builtin_amdgcn_mfma_f32_16x16x32_f16(ahi[ko], wlo, acc[fo], 0, 0, 0);
        }
#pragma unroll
    for (int fo = 0; fo < 4; ++fo)
#pragma unroll
        for (int m = 0; m < 4; ++m)
            st[s][b][g * 4 + m][fo * 16 + l15] = (_Float16)acc[fo][m];
    __syncthreads();
    // repack: 2048 uint2 (2 supports x 16 rows x 64 f), 4 per thread,
    // ss/rr uniform per iteration, f = consecutive lanes -> coalesced.
#pragma unroll
    for (int i = 0; i < 4; ++i) {
        const int idx = tid + i * 512;
        const int ss = idx >> 10, rr = (idx >> 6) & 15, f = idx & 63;
        const unsigned short u0 = __builtin_bit_cast(unsigned short, st[ss][0][rr][f]);
        const unsigned short u1 = __builtin_bit_cast(unsigned short, st[ss][1][rr][f]);
        const unsigned short u2 = __builtin_bit_cast(unsigned short, st[ss][2][rr][f]);
        const unsigned short u3 = __builtin_bit_cast(unsigned short, st[ss][3][rr][f]);
        uint2* const dst = ss ? pre2 : pre1;
        dst[(size_t)(r0 + rr) * FF + f] =
            make_uint2((unsigned)u0 | ((unsigned)u1 << 16),
                       (unsigned)u2 | ((unsigned)u3 << 16));
    }
}

// ---------------- bin edges (no rank — counts are fire-and-forget) ----------
__global__ void bin_edges(const int* __restrict__ r1, const int* __restrict__ c1,
                          const float* __restrict__ v1,
                          const int* __restrict__ r2, const int* __restrict__ c2,
                          const float* __restrict__ v2,
                          int* __restrict__ counts, int* __restrict__ bcnt,
                          int4* __restrict__ bepack, int cap, int E) {
    __shared__ int lcnt[NBKT], lbase[NBKT];
    const int tid = threadIdx.x;
    if (tid < NBKT) lcnt[tid] = 0;
    __syncthreads();
    const int base = blockIdx.x * BIN_CHUNK;
    int bk[BIN_U], lrk[BIN_U], sr[BIN_U], co[BIN_U], va[BIN_U];
#pragma unroll
    for (int u = 0; u < BIN_U; ++u) {
        const int e = base + u * BIN_T + tid;
        int srow = -1, col = 0, val = 0;
        if (e < E)          { srow = r1[e];          col = c1[e];     val = __float_as_int(v1[e]); }
        else if (e < 2 * E) { srow = NN + r2[e - E]; col = c2[e - E]; val = __float_as_int(v2[e - E]); }
        if (srow >= 0) {
            atomicAdd(&counts[srow], 1);                // no return -> no stall
            const int b = srow / OCT;
            bk[u] = b; sr[u] = srow; co[u] = col; va[u] = val;
            lrk[u] = atomicAdd(&lcnt[b], 1);            // LDS, block-local pack
        } else bk[u] = -1;
    }
    __syncthreads();
    if (tid < NBKT) lbase[tid] = lcnt[tid] ? atomicAdd(&bcnt[tid], lcnt[tid]) : 0;
    __syncthreads();
#pragma unroll
    for (int u = 0; u < BIN_U; ++u) {
        if (bk[u] >= 0) {
            const int pos = bk[u] * cap + lbase[bk[u]] + lrk[u];
            bepack[pos] = make_int4(sr[u], co[u], va[u], 0);
        }
    }
}

// ---------------- hierarchical scan over 2N row counts (partial only) -------
__global__ void scan_partial(const int* __restrict__ counts,
                             int* __restrict__ rowptrP, int* __restrict__ blocksum) {
    __shared__ int buf[256];
    const int tid = threadIdx.x;
    const int i = blockIdx.x * 256 + tid;
    const int v = (i < NN2) ? counts[i] : 0;
    buf[tid] = v;
    __syncthreads();
#pragma unroll
    for (int off = 1; off < 256; off <<= 1) {
        int t = (tid >= off) ? buf[tid - off] : 0;
        __syncthreads();
        buf[tid] += t;
        __syncthreads();
    }
    if (i < NN2) rowptrP[i] = buf[tid] - v;   // exclusive within block
    if (tid == 255) blocksum[blockIdx.x] = buf[255];
}

// Exclusive scan of the 391 block sums, in place.
__global__ void scan_sums(int* __restrict__ blocksum) {
    __shared__ int buf[512];
    const int tid = threadIdx.x;
    const int v = (tid < SCAN_BLOCKS) ? blocksum[tid] : 0;
    buf[tid] = v;
    __syncthreads();
#pragma unroll
    for (int off = 1; off < 512; off <<= 1) {
        int t = (tid >= off) ? buf[tid - off] : 0;
        __syncthreads();
        buf[tid] += t;
        __syncthreads();
    }
    if (tid < SCAN_BLOCKS) blocksum[tid] = buf[tid] - v;
}

// ---------------- absolute rowptr + mutable cursor copy ---------------------
__global__ void make_ptrs(const int* __restrict__ rowptrP, const int* __restrict__ blocksum,
                          int* __restrict__ rowptrA, int* __restrict__ rowcur, int totalE) {
    const int i = blockIdx.x * 256 + threadIdx.x;
    if (i < NN2) {
        const int a = rowptrP[i] + blocksum[i >> 8];
        rowptrA[i] = a;
        rowcur[i]  = a;
    } else if (i == NN2) {
        rowptrA[NN2] = totalE;
    }
}

// ---------------- scatter, octant-pinned; claims slot via cursor ------------
__global__ void scatter_binned(const int4* __restrict__ bepack, const int* __restrict__ bcnt,
                               int* __restrict__ rowcur,
                               int2* __restrict__ cv, int cap) {
    const int o = blockIdx.x & 7;
    const int k = blockIdx.x >> 3;
    const int K = gridDim.x >> 3;
#pragma unroll
    for (int s = 0; s < 2; ++s) {
        const int b = s * 8 + o;
        const int beg = b * cap, end = b * cap + bcnt[b];
        for (int i = beg + k * 256 + threadIdx.x; i < end; i += K * 256) {
            const int4 e = bepack[i];     // {srow, col, val, 0}
            const int pos = atomicAdd(&rowcur[e.x], 1);
            cv[pos] = make_int2(e.y, e.z);
        }
    }
}

// ---------------- fused SpMM: out = relu(A1·pre1 + A2·pre2 + b) -------------
__device__ __forceinline__ void acc_seg(int beg, int end,
                                        const int2* __restrict__ cv,
                                        const uint2* __restrict__ pre, int f,
                                        float& a0, float& a1, float& a2, float& a3) {
    int j = beg;
    for (; j + 4 <= end; j += 4) {                 // 4 independent gathers in flight
        const int2 e0 = cv[j], e1 = cv[j + 1], e2 = cv[j + 2], e3 = cv[j + 3];
        const uint2 g0 = pre[(size_t)e0.x * FF + f];
        const uint2 g1 = pre[(size_t)e1.x * FF + f];
        const uint2 g2 = pre[(size_t)e2.x * FF + f];
        const uint2 g3 = pre[(size_t)e3.x * FF + f];
        const float v0 = __int_as_float(e0.y), v1 = __int_as_float(e1.y);
        const float v2 = __int_as_float(e2.y), v3 = __int_as_float(e3.y);
        float2 a, b;
        a = __half22float2(*(const __half2*)&g0.x); b = __half22float2(*(const __half2*)&g0.y);
        a0 += v0 * a.x; a1 += v0 * a.y; a2 += v0 * b.x; a3 += v0 * b.y;
        a = __half22float2(*(const __half2*)&g1.x); b = __half22float2(*(const __half2*)&g1.y);
        a0 += v1 * a.x; a1 += v1 * a.y; a2 += v1 * b.x; a3 += v1 * b.y;
        a = __half22float2(*(const __half2*)&g2.x); b = __half22float2(*(const __half2*)&g2.y);
        a0 += v2 * a.x; a1 += v2 * a.y; a2 += v2 * b.x; a3 += v2 * b.y;
        a = __half22float2(*(const __half2*)&g3.x); b = __half22float2(*(const __half2*)&g3.y);
        a0 += v3 * a.x; a1 += v3 * a.y; a2 += v3 * b.x; a3 += v3 * b.y;
    }
    for (; j < end; ++j) {
        const int2 e = cv[j];
        const uint2 g = pre[(size_t)e.x * FF + f];
        const float v = __int_as_float(e.y);
        const float2 a = __half22float2(*(const __half2*)&g.x);
        const float2 b = __half22float2(*(const __half2*)&g.y);
        a0 += v * a.x; a1 += v * a.y; a2 += v * b.x; a3 += v * b.y;
    }
}

__global__ void spmm_fused(const int* __restrict__ rowptrA,
                           const int2* __restrict__ cv,
                           const uint2* __restrict__ pre1, const uint2* __restrict__ pre2,
                           const float* __restrict__ bias, float* __restrict__ out) {
    const int tid = blockIdx.x * blockDim.x + threadIdx.x;
    const int r = tid >> 6;
    if (r >= NN) return;
    const int f = tid & 63;
    const int b0  = rowptrA[r];
    const int e0_ = rowptrA[r + 1];
    const int b1  = rowptrA[NN + r];
    const int e1_ = rowptrA[NN + r + 1];
    float a0 = 0.f, a1 = 0.f, a2 = 0.f, a3 = 0.f;
    acc_seg(b0, e0_, cv, pre1, f, a0, a1, a2, a3);
    acc_seg(b1, e1_, cv, pre2, f, a0, a1, a2, a3);
    const float bf = bias[f];
    a0 += bf; a1 += bf; a2 += bf; a3 += bf;
    const size_t o = (size_t)r * FF + f;
    const size_t s = (size_t)NN * FF;
    out[o]         = a0 > 0.f ? a0 : 0.f;
    out[o + s]     = a1 > 0.f ? a1 : 0.f;
    out[o + 2 * s] = a2 > 0.f ? a2 : 0.f;
    out[o + 3 * s] = a3 > 0.f ? a3 : 0.f;
}

extern "C" void kernel_launch(void* const* d_in, const int* in_sizes, int n_in,
                              void* d_out, int out_size, void* d_ws, size_t ws_size,
                              hipStream_t stream) {
    const float* x     = (const float*)d_in[0];
    const int*   rows1 = (const int*)d_in[1];
    const int*   cols1 = (const int*)d_in[2];
    const float* vals1 = (const float*)d_in[3];
    const int*   rows2 = (const int*)d_in[4];
    const int*   cols2 = (const int*)d_in[5];
    const float* vals2 = (const float*)d_in[6];
    const float* W1    = (const float*)d_in[7];
    const float* W2    = (const float*)d_in[8];
    const float* bias  = (const float*)d_in[9];
    float* out = (float*)d_out;

    const int E = in_sizes[1];
    const int cap = E / 8 + E / 64 + 4096;   // fixed bucket capacity (huge margin)

    // Workspace (~66 MB). Region P (51.2 MB) time-shared:
    //   build  : bepack[16*cap] int4 (~30 MB), dead after scatter
    //   compute: pre1 | pre2 (51.2 MB), born at gemm
    char* w = (char*)d_ws;
    auto align = [](size_t v) { return (v + 255) & ~(size_t)255; };
    char* P = w;                                  w += align((size_t)2 * NN * FF * 8);
    int2*  cv       = (int2*)w;                   w += align((size_t)2 * E * 8);
    int*   counts   = (int*)w;                    w += align(((size_t)NN2 + NBKT) * 4);
    int*   rowptrP  = (int*)w;                    w += align(((size_t)NN2 + 1) * 4);
    int*   blocksum = (int*)w;                    w += align((size_t)SCAN_BLOCKS * 4);
    int*   rowptrA  = (int*)w;                    w += align(((size_t)NN2 + 1) * 4);
    int*   rowcur   = (int*)w;                    w += align((size_t)NN2 * 4);
    uint4* wfrag    = (uint4*)w;                  w += align((size_t)32 * 64 * 16);
    int*   bcnt = counts + NN2;                   // zeroed with counts
    int4*  bepack = (int4*)P;
    uint2* pre1 = (uint2*)P;
    uint2* pre2 = (uint2*)(P + (size_t)NN * FF * 8);

    const int gemm_blocks = NN / 16;                              // 3125
    const int bin_blocks  = (2 * E + BIN_CHUNK - 1) / BIN_CHUNK;  // 1563
    const int ptr_blocks  = (NN2 + 1 + 255) / 256;                // 392
    const int spmm_blocks = (NN * FF + 255) / 256;                // 12500

    build_wfrag<<<8, 256, 0, stream>>>(W1, W2, wfrag);
    hipMemsetAsync(counts, 0, ((size_t)NN2 + NBKT) * 4, stream);
    bin_edges<<<bin_blocks, BIN_T, 0, stream>>>(rows1, cols1, vals1,
                                                rows2, cols2, vals2,
                                                counts, bcnt, bepack, cap, E);
    scan_partial<<<SCAN_BLOCKS, 256, 0, stream>>>(counts, rowptrP, blocksum);
    scan_sums<<<1, 512, 0, stream>>>(blocksum);
    make_ptrs<<<ptr_blocks, 256, 0, stream>>>(rowptrP, blocksum, rowptrA, rowcur, 2 * E);
    scatter_binned<<<8 * 392, 256, 0, stream>>>(bepack, bcnt, rowcur, cv, cap);
    gemm_mfma<<<gemm_blocks, 512, 0, stream>>>(x, wfrag, pre1, pre2);
    spmm_fused<<<spmm_blocks, 256, 0, stream>>>(rowptrA, cv, pre1, pre2, bias, out);
}

// Round 6
// 323.267 us; speedup vs baseline: 1.2199x; 1.2199x over previous
//
#include <hip/hip_runtime.h>
#include <hip/hip_fp16.h>

// GCN layer: relu(A1·(xW1) + A2·(xW2) + b), B=4, N=50000, F=64, E=800000.
// fp32 in/out, int32 indices. pre stored fp16 (gather operand; fp32 accum).
// Row space concatenated over both supports: srow in [0, 2N); bucket =
// srow/6250 (16 buckets = 2 supports x 8 octants). Chain:
//   build_wfrag -> memset -> FUSED{gemm_mfma | bin_edges_rank} -> scan_partial
//   -> scan_sums -> make_ptrs -> scatter (rank-based) -> fused spmm.
// bepack lives in d_out (dead until spmm writes it) so bin and gemm can run
// concurrently without the old region-P time-share hazard.
// R9: gemm on split-fp16 3-term MFMA; accuracy = fp32 GEMM. 398->347us.
// R10: dual-stream spmm + nt stores: NEUTRAL -> spmm memory-throughput-bound.
// R11: s1/s2 split + gemm LDS-drop: REGRESSED (bundled; reverted).
//     Diagnostic: bin = 78us, occ 25%, VALU 2% -> atomic-return-latency bound.
// R12: bin BIN_U 8->2: NEUTRAL (in-flight atomics/CU unchanged net).
// R13: fire-and-forget + cursor-scatter: REGRESSED 350->394 (latency moved
//     to scatter, not removed). Atomic round-trips are conserved -> HIDE them.
// R14: fuse bin INTO gemm dispatch (1:4 block interleave, disjoint data).
//     bin's idle atomic-wait slots absorb gemm's compute. Rest = R1 config.
#define NB 4
#define NN 50000
#define FF 64
#define NN2 (2 * NN)
#define OCT 6250
#define NBKT 16
#define SCAN_BLOCKS ((NN2 + 255) / 256)   // 391
#define BIN_U 4
#define BIN_T 512
#define BIN_CHUNK (BIN_U * BIN_T)         // 2048 edges per bin block
#define STP 68                            // padded staging stride (halves)
#define GEMM_BLOCKS (NN / 16)             // 3125
#define BIN_BLOCKS  ((2 * 800000 + BIN_CHUNK - 1) / BIN_CHUNK)  // 782

typedef _Float16 half8 __attribute__((ext_vector_type(8)));
typedef float    f32x4 __attribute__((ext_vector_type(4)));

// ---------------- W fragments for mfma_f32_16x16x32_f16 ---------------------
// B-operand layout (16x16x32): lane l holds col = l&15, k = (l>>4)*8 + j,
// j=0..7, packed k-ascending as half8 (4 VGPRs). 32 frags:
//   frag = s*16 + part*8 + ko*4 + fo   (s: support, part: hi/lo split,
//   ko: k-half 0..1, fo: 16-col output tile 0..3).  32*64*16B = 32 KB.
__global__ void build_wfrag(const float* __restrict__ W1, const float* __restrict__ W2,
                            uint4* __restrict__ wfrag) {
    const int t = blockIdx.x * 256 + threadIdx.x;    // 0..2047
    if (t >= 32 * 64) return;
    const int lane = t & 63;
    const int frag = t >> 6;
    const int fo   = frag & 3;
    const int ko   = (frag >> 2) & 1;
    const int part = (frag >> 3) & 1;
    const int s    = frag >> 4;
    const float* W = s ? W2 : W1;
    const int col = fo * 16 + (lane & 15);
    const int k0  = ko * 32 + (lane >> 4) * 8;
    half8 h;
#pragma unroll
    for (int j = 0; j < 8; ++j) {
        const float w = W[(k0 + j) * FF + col];
        const _Float16 hi = (_Float16)w;
        h[j] = part ? (_Float16)(w - (float)hi) : hi;
    }
    wfrag[t] = __builtin_bit_cast(uint4, h);
}

// ---------------- FUSED: gemm tiles (4 of 5 blocks) + bin chunks (1 of 5) ---
// gemm: block = 8 waves; wave w: support s=w>>2, batch b=w&3, rows r0..r0+15.
// A-operand (x rows, fp32->hi/lo fp16): lane l holds row=l&15, k=(l>>4)*8+j.
// 24 MFMA/wave. D: row=(l>>4)*4+m, col=l&15. Output staged in LDS (stride 68
// halves, conflict-free) and repacked to the uint2 fp16 layout spmm consumes.
// bin: 2048 edges/block; global rank via atomicAdd-with-return (its ~700cy
// round-trip latency hides under co-resident gemm blocks' MFMA/stream work);
// bucket-packed bepack write via LDS-block aggregation.
__global__ __launch_bounds__(512, 2) void fused_gemm_bin(
        const float* __restrict__ x, const uint4* __restrict__ wfrag,
        uint2* __restrict__ pre1, uint2* __restrict__ pre2,
        const int* __restrict__ r1, const int* __restrict__ c1,
        const float* __restrict__ v1,
        const int* __restrict__ r2, const int* __restrict__ c2,
        const float* __restrict__ v2,
        int* __restrict__ counts, int* __restrict__ bcnt,
        int4* __restrict__ bepack, int cap, int E) {
    __shared__ uint4 fr[32][64];            // 32 KB (gemm path)
    __shared__ _Float16 st[2][4][16][STP];  // 17.4 KB (gemm path)
    __shared__ int lcnt[NBKT], lbase[NBKT]; // (bin path)
    const int bid = blockIdx.x;
    const int tid = threadIdx.x;

    if (bid % 5 == 0) {
        // ---------------- bin path ----------------
        const int bin_idx = bid / 5;
        if (tid < NBKT) lcnt[tid] = 0;
        __syncthreads();
        const int base = bin_idx * BIN_CHUNK;
        int bk[BIN_U], lrk[BIN_U], sr[BIN_U], rk[BIN_U], co[BIN_U], va[BIN_U];
#pragma unroll
        for (int u = 0; u < BIN_U; ++u) {
            const int e = base + u * BIN_T + tid;
            int srow = -1, col = 0, val = 0;
            if (e < E)          { srow = r1[e];          col = c1[e];     val = __float_as_int(v1[e]); }
            else if (e < 2 * E) { srow = NN + r2[e - E]; col = c2[e - E]; val = __float_as_int(v2[e - E]); }
            if (srow >= 0) {
                rk[u] = atomicAdd(&counts[srow], 1);        // global per-row rank
                const int b = srow / OCT;
                bk[u] = b; sr[u] = srow; co[u] = col; va[u] = val;
                lrk[u] = atomicAdd(&lcnt[b], 1);            // LDS, block-local
            } else bk[u] = -1;
        }
        __syncthreads();
        if (tid < NBKT) lbase[tid] = lcnt[tid] ? atomicAdd(&bcnt[tid], lcnt[tid]) : 0;
        __syncthreads();
#pragma unroll
        for (int u = 0; u < BIN_U; ++u) {
            if (bk[u] >= 0) {
                const int pos = bk[u] * cap + lbase[bk[u]] + lrk[u];
                bepack[pos] = make_int4(sr[u], rk[u], co[u], va[u]);
            }
        }
        return;
    }

    // ---------------- gemm path ----------------
    const int gemm_idx = bid - bid / 5 - 1;     // dense 0..GEMM_BLOCKS-1
#pragma unroll
    for (int i = 0; i < 4; ++i) {               // stage all 32 frags, coalesced
        const int idx = tid + i * 512;
        fr[idx >> 6][idx & 63] = wfrag[idx];
    }
    const int wid = tid >> 6, lane = tid & 63;
    const int s = wid >> 2, b = wid & 3;
    const int r0 = gemm_idx * 16;
    const int l15 = lane & 15, g = lane >> 4;
    // A: 64B/lane of x row l15, fully coalesced across the wave (4 KB/wave)
    const float4* xp = (const float4*)(x + ((size_t)b * NN + r0 + l15) * FF);
    const float4 A0 = xp[g * 2],     A1 = xp[g * 2 + 1];
    const float4 A2 = xp[8 + g * 2], A3 = xp[8 + g * 2 + 1];
    const float av[16] = {A0.x, A0.y, A0.z, A0.w, A1.x, A1.y, A1.z, A1.w,
                          A2.x, A2.y, A2.z, A2.w, A3.x, A3.y, A3.z, A3.w};
    half8 ahi[2], alo[2];
#pragma unroll
    for (int ko = 0; ko < 2; ++ko)
#pragma unroll
        for (int j = 0; j < 8; ++j) {
            const float v = av[ko * 8 + j];
            const _Float16 hi = (_Float16)v;
            ahi[ko][j] = hi;
            alo[ko][j] = (_Float16)(v - (float)hi);
        }
    __syncthreads();
    f32x4 acc[4] = {{0.f, 0.f, 0.f, 0.f}, {0.f, 0.f, 0.f, 0.f},
                    {0.f, 0.f, 0.f, 0.f}, {0.f, 0.f, 0.f, 0.f}};
#pragma unroll
    for (int fo = 0; fo < 4; ++fo)
#pragma unroll
        for (int ko = 0; ko < 2; ++ko) {
            const half8 whi = *(const half8*)&fr[s * 16 + ko * 4 + fo][lane];
            const half8 wlo = *(const half8*)&fr[s * 16 + 8 + ko * 4 + fo][lane];
            acc[fo] = __builtin_amdgcn_mfma_f32_16x16x32_f16(ahi[ko], whi, acc[fo], 0, 0, 0);
            acc[fo] = __builtin_amdgcn_mfma_f32_16x16x32_f16(alo[ko], whi, acc[fo], 0, 0, 0);
            acc[fo] = __builtin_amdgcn_mfma_f32_16x16x32_f16(ahi[ko], wlo, acc[fo], 0, 0, 0);
        }
#pragma unroll
    for (int fo = 0; fo < 4; ++fo)
#pragma unroll
        for (int m = 0; m < 4; ++m)
            st[s][b][g * 4 + m][fo * 16 + l15] = (_Float16)acc[fo][m];
    __syncthreads();
    // repack: 2048 uint2 (2 supports x 16 rows x 64 f), 4 per thread,
    // ss/rr uniform per iteration, f = consecutive lanes -> coalesced.
#pragma unroll
    for (int i = 0; i < 4; ++i) {
        const int idx = tid + i * 512;
        const int ss = idx >> 10, rr = (idx >> 6) & 15, f = idx & 63;
        const unsigned short u0 = __builtin_bit_cast(unsigned short, st[ss][0][rr][f]);
        const unsigned short u1 = __builtin_bit_cast(unsigned short, st[ss][1][rr][f]);
        const unsigned short u2 = __builtin_bit_cast(unsigned short, st[ss][2][rr][f]);
        const unsigned short u3 = __builtin_bit_cast(unsigned short, st[ss][3][rr][f]);
        uint2* const dst = ss ? pre2 : pre1;
        dst[(size_t)(r0 + rr) * FF + f] =
            make_uint2((unsigned)u0 | ((unsigned)u1 << 16),
                       (unsigned)u2 | ((unsigned)u3 << 16));
    }
}

// ---------------- hierarchical scan over 2N row counts (partial only) -------
__global__ void scan_partial(const int* __restrict__ counts,
                             int* __restrict__ rowptrP, int* __restrict__ blocksum) {
    __shared__ int buf[256];
    const int tid = threadIdx.x;
    const int i = blockIdx.x * 256 + tid;
    const int v = (i < NN2) ? counts[i] : 0;
    buf[tid] = v;
    __syncthreads();
#pragma unroll
    for (int off = 1; off < 256; off <<= 1) {
        int t = (tid >= off) ? buf[tid - off] : 0;
        __syncthreads();
        buf[tid] += t;
        __syncthreads();
    }
    if (i < NN2) rowptrP[i] = buf[tid] - v;   // exclusive within block
    if (tid == 255) blocksum[blockIdx.x] = buf[255];
}

// Exclusive scan of the 391 block sums, in place.
__global__ void scan_sums(int* __restrict__ blocksum) {
    __shared__ int buf[512];
    const int tid = threadIdx.x;
    const int v = (tid < SCAN_BLOCKS) ? blocksum[tid] : 0;
    buf[tid] = v;
    __syncthreads();
#pragma unroll
    for (int off = 1; off < 512; off <<= 1) {
        int t = (tid >= off) ? buf[tid - off] : 0;
        __syncthreads();
        buf[tid] += t;
        __syncthreads();
    }
    if (tid < SCAN_BLOCKS) blocksum[tid] = buf[tid] - v;
}

// ---------------- absolute rowptr -------------------------------------------
__global__ void make_ptrs(const int* __restrict__ rowptrP, const int* __restrict__ blocksum,
                          int* __restrict__ rowptrA, int totalE) {
    const int i = blockIdx.x * 256 + threadIdx.x;
    if (i < NN2)       rowptrA[i] = rowptrP[i] + blocksum[i >> 8];
    else if (i == NN2) rowptrA[NN2] = totalE;
}

// ---------------- scatter, octant-pinned, rank-based ------------------------
__global__ void scatter_binned(const int4* __restrict__ bepack, const int* __restrict__ bcnt,
                               const int* __restrict__ rowptrA,
                               int2* __restrict__ cv, int cap) {
    const int o = blockIdx.x & 7;
    const int k = blockIdx.x >> 3;
    const int K = gridDim.x >> 3;
#pragma unroll
    for (int s = 0; s < 2; ++s) {
        const int b = s * 8 + o;
        const int beg = b * cap, end = b * cap + bcnt[b];
        for (int i = beg + k * 256 + threadIdx.x; i < end; i += K * 256) {
            const int4 e = bepack[i];     // {srow, rank, col, val}
            const int pos = rowptrA[e.x] + e.y;
            cv[pos] = make_int2(e.z, e.w);
        }
    }
}

// ---------------- fused SpMM: out = relu(A1·pre1 + A2·pre2 + b) -------------
__device__ __forceinline__ void acc_seg(int beg, int end,
                                        const int2* __restrict__ cv,
                                        const uint2* __restrict__ pre, int f,
                                        float& a0, float& a1, float& a2, float& a3) {
    int j = beg;
    for (; j + 4 <= end; j += 4) {                 // 4 independent gathers in flight
        const int2 e0 = cv[j], e1 = cv[j + 1], e2 = cv[j + 2], e3 = cv[j + 3];
        const uint2 g0 = pre[(size_t)e0.x * FF + f];
        const uint2 g1 = pre[(size_t)e1.x * FF + f];
        const uint2 g2 = pre[(size_t)e2.x * FF + f];
        const uint2 g3 = pre[(size_t)e3.x * FF + f];
        const float v0 = __int_as_float(e0.y), v1 = __int_as_float(e1.y);
        const float v2 = __int_as_float(e2.y), v3 = __int_as_float(e3.y);
        float2 a, b;
        a = __half22float2(*(const __half2*)&g0.x); b = __half22float2(*(const __half2*)&g0.y);
        a0 += v0 * a.x; a1 += v0 * a.y; a2 += v0 * b.x; a3 += v0 * b.y;
        a = __half22float2(*(const __half2*)&g1.x); b = __half22float2(*(const __half2*)&g1.y);
        a0 += v1 * a.x; a1 += v1 * a.y; a2 += v1 * b.x; a3 += v1 * b.y;
        a = __half22float2(*(const __half2*)&g2.x); b = __half22float2(*(const __half2*)&g2.y);
        a0 += v2 * a.x; a1 += v2 * a.y; a2 += v2 * b.x; a3 += v2 * b.y;
        a = __half22float2(*(const __half2*)&g3.x); b = __half22float2(*(const __half2*)&g3.y);
        a0 += v3 * a.x; a1 += v3 * a.y; a2 += v3 * b.x; a3 += v3 * b.y;
    }
    for (; j < end; ++j) {
        const int2 e = cv[j];
        const uint2 g = pre[(size_t)e.x * FF + f];
        const float v = __int_as_float(e.y);
        const float2 a = __half22float2(*(const __half2*)&g.x);
        const float2 b = __half22float2(*(const __half2*)&g.y);
        a0 += v * a.x; a1 += v * a.y; a2 += v * b.x; a3 += v * b.y;
    }
}

__global__ void spmm_fused(const int* __restrict__ rowptrA,
                           const int2* __restrict__ cv,
                           const uint2* __restrict__ pre1, const uint2* __restrict__ pre2,
                           const float* __restrict__ bias, float* __restrict__ out) {
    const int tid = blockIdx.x * blockDim.x + threadIdx.x;
    const int r = tid >> 6;
    if (r >= NN) return;
    const int f = tid & 63;
    const int b0  = rowptrA[r];
    const int e0_ = rowptrA[r + 1];
    const int b1  = rowptrA[NN + r];
    const int e1_ = rowptrA[NN + r + 1];
    float a0 = 0.f, a1 = 0.f, a2 = 0.f, a3 = 0.f;
    acc_seg(b0, e0_, cv, pre1, f, a0, a1, a2, a3);
    acc_seg(b1, e1_, cv, pre2, f, a0, a1, a2, a3);
    const float bf = bias[f];
    a0 += bf; a1 += bf; a2 += bf; a3 += bf;
    const size_t o = (size_t)r * FF + f;
    const size_t s = (size_t)NN * FF;
    out[o]         = a0 > 0.f ? a0 : 0.f;
    out[o + s]     = a1 > 0.f ? a1 : 0.f;
    out[o + 2 * s] = a2 > 0.f ? a2 : 0.f;
    out[o + 3 * s] = a3 > 0.f ? a3 : 0.f;
}

extern "C" void kernel_launch(void* const* d_in, const int* in_sizes, int n_in,
                              void* d_out, int out_size, void* d_ws, size_t ws_size,
                              hipStream_t stream) {
    const float* x     = (const float*)d_in[0];
    const int*   rows1 = (const int*)d_in[1];
    const int*   cols1 = (const int*)d_in[2];
    const float* vals1 = (const float*)d_in[3];
    const int*   rows2 = (const int*)d_in[4];
    const int*   cols2 = (const int*)d_in[5];
    const float* vals2 = (const float*)d_in[6];
    const float* W1    = (const float*)d_in[7];
    const float* W2    = (const float*)d_in[8];
    const float* bias  = (const float*)d_in[9];
    float* out = (float*)d_out;

    const int E = in_sizes[1];
    const int cap = E / 8 + E / 64 + 4096;   // fixed bucket capacity (huge margin)

    // Workspace (~65 MB). bepack (29.9 MB) lives in d_out (dead until spmm),
    // so gemm (writes pre) and bin (writes bepack) can run concurrently.
    char* w = (char*)d_ws;
    auto align = [](size_t v) { return (v + 255) & ~(size_t)255; };
    char* P = w;                                  w += align((size_t)2 * NN * FF * 8);
    int2*  cv       = (int2*)w;                   w += align((size_t)2 * E * 8);
    int*   counts   = (int*)w;                    w += align(((size_t)NN2 + NBKT) * 4);
    int*   rowptrP  = (int*)w;                    w += align(((size_t)NN2 + 1) * 4);
    int*   blocksum = (int*)w;                    w += align((size_t)SCAN_BLOCKS * 4);
    int*   rowptrA  = (int*)w;                    w += align(((size_t)NN2 + 1) * 4);
    uint4* wfrag    = (uint4*)w;                  w += align((size_t)32 * 64 * 16);
    int*   bcnt = counts + NN2;                   // zeroed with counts
    int4*  bepack = (int4*)d_out;                 // scratch until spmm
    uint2* pre1 = (uint2*)P;
    uint2* pre2 = (uint2*)(P + (size_t)NN * FF * 8);

    const int bin_blocks   = (2 * E + BIN_CHUNK - 1) / BIN_CHUNK;  // 782
    const int fused_blocks = GEMM_BLOCKS + bin_blocks;             // 3907
    const int ptr_blocks   = (NN2 + 1 + 255) / 256;                // 392
    const int spmm_blocks  = (NN * FF + 255) / 256;                // 12500

    build_wfrag<<<8, 256, 0, stream>>>(W1, W2, wfrag);
    hipMemsetAsync(counts, 0, ((size_t)NN2 + NBKT) * 4, stream);
    fused_gemm_bin<<<fused_blocks, 512, 0, stream>>>(
        x, wfrag, pre1, pre2,
        rows1, cols1, vals1, rows2, cols2, vals2,
        counts, bcnt, bepack, cap, E);
    scan_partial<<<SCAN_BLOCKS, 256, 0, stream>>>(counts, rowptrP, blocksum);
    scan_sums<<<1, 512, 0, stream>>>(blocksum);
    make_ptrs<<<ptr_blocks, 256, 0, stream>>>(rowptrP, blocksum, rowptrA, 2 * E);
    scatter_binned<<<8 * 392, 256, 0, stream>>>(bepack, bcnt, rowptrA, cv, cap);
    spmm_fused<<<spmm_blocks, 256, 0, stream>>>(rowptrA, cv, pre1, pre2, bias, out);
}